// Round 2
// baseline (816.900 us; speedup 1.0000x reference)
//
#include <hip/hip_runtime.h>

// Fused 2-layer LSTM (B=4096, S=512, H=64) + dense(64->32 relu)->dense(32->24).
// R5: R4 structure (1024-thread WG, 16 waves = 4/SIMD, grid=256 = 1 WG/CU) with
// the register-allocator occupancy target PINNED via amdgpu_waves_per_eu(2,4).
// R4 post-mortem: LLVM targeted 8 waves/EU (2 WGs/CU is thread-feasible), clamped
// VGPR to 64 and spilled ~60B/thread to scratch (WRITE_SIZE 0.38->15.8 MB); the
// per-step scratch round-trips serialized the t-loop (2076 -> 3860 cy/step).
// Grid=256 only ever runs 1 WG/CU, so that occupancy was unreachable — cap the
// target at 4 waves/EU so VGPR budget = 128 and no spill.
// Waves: (layer, col-tile, row-half). rh=0/1 wave pairs duplicate the MFMAs
// (MFMA pipe ~20% busy, duplication ~free) but split gate math + h-write 2 rows
// each, so per-SIMD VALU work matches R3 while 4 waves/SIMD hide the serial
// chain (barrier -> ds_read -> MFMA -> exp2 chain -> ds_write) of each other.
// Single barrier/step via parity double-buffered h1/h2 (layer-2 delayed 1 step:
// z2[t-1] = b2 + Wih2@h1[t-1] + Whh2@h2[t-2]).
// Gate math: 5 exp + 2 rcp per element (i/f/g denominators merged).

typedef __attribute__((ext_vector_type(8))) short bf16x8;
typedef __attribute__((ext_vector_type(4))) float floatx4;

#define SEQ 512
#define HID 64
#define LOG2E 1.4426950408889634f

__device__ inline floatx4 MFMA(bf16x8 a, bf16x8 b, floatx4 c) {
    return __builtin_amdgcn_mfma_f32_16x16x32_bf16(a, b, c, 0, 0, 0);
}
__device__ inline short f2bf(float f) {
    __bf16 b = (__bf16)f;
    return __builtin_bit_cast(short, b);
}
__device__ inline float exp2_fast(float x) {
#if __has_builtin(__builtin_amdgcn_exp2f)
    return __builtin_amdgcn_exp2f(x);
#else
    return __expf(x * 0.6931471805599453f);
#endif
}
__device__ inline float rcp_fast(float x) { return __builtin_amdgcn_rcpf(x); }

// z* pre-scaled: zi=-i*log2e, zf=-f*log2e, zg=-2g*log2e, zo=-o*log2e.
// c' = [c*(1+ei)(1+eg) + (1-eg)(1+ef)] / [(1+ef)(1+ei)(1+eg)]  (merged rcp)
// h  = sigm(o)*tanh(c') = (1-ec)/((1+eo)(1+ec)),  ec = e^{-2c'} (clamped)
__device__ inline float lstm_gate(float zi, float zf, float zg, float zo, float& c) {
    float ei = exp2_fast(zi);
    float ef = exp2_fast(zf);
    float eg = exp2_fast(zg);
    float eo = exp2_fast(zo);
    float P  = (1.0f + ei) * (1.0f + eg);
    float F  = 1.0f + ef;
    float num = c * P + (1.0f - eg) * F;
    c = num * rcp_fast(P * F);
    float ec = exp2_fast(fminf(c * (-2.0f * LOG2E), 40.0f));
    return (1.0f - ec) * rcp_fast((1.0f + eo) * (1.0f + ec));
}

__global__ __launch_bounds__(1024)
__attribute__((amdgpu_waves_per_eu(2, 4)))
void lstm_fused(
    const float* __restrict__ x,
    const float* __restrict__ Wih1, const float* __restrict__ Whh1,
    const float* __restrict__ bih1, const float* __restrict__ bhh1,
    const float* __restrict__ Wih2, const float* __restrict__ Whh2,
    const float* __restrict__ bih2, const float* __restrict__ bhh2,
    const float* __restrict__ Wd1,  const float* __restrict__ bd1,
    const float* __restrict__ Wd2,  const float* __restrict__ bd2,
    float* __restrict__ out)
{
    const int tid  = threadIdx.x;
    const int wid  = tid >> 6;        // 0..15
    const int ct   = wid & 3;         // column-tile (h-cols [16ct,16ct+16))
    const int is2  = (wid >> 2) & 1;  // 0: layer-1 wave, 1: layer-2 wave
    const int rh   = wid >> 3;        // row-half: handles r in {2rh, 2rh+1}
    const int lane = tid & 63;
    const int l15  = lane & 15;
    const int quad = lane >> 4;
    const int b0   = blockIdx.x * 16;

    __shared__ __align__(16) float x_s[16][516];
    __shared__ __align__(16) short h1_s[2][16][72];
    __shared__ __align__(16) short h2_s[2][16][72];
    __shared__ float y1_s[16][32];

    // ---- stage x tile (16 rows x 512 f32), 1024 threads ----
    {
        const int row = wid;               // 16 rows, one wave each
        const int c0  = lane * 8;          // 64 lanes x 8 floats = 512
        const float4* src = reinterpret_cast<const float4*>(x + (size_t)(b0 + row) * SEQ + c0);
        float4* dst = reinterpret_cast<float4*>(&x_s[row][c0]);
        dst[0] = src[0];
        dst[1] = src[1];
    }
    for (int i = tid; i < 2 * 16 * 72; i += 1024) {
        (&h1_s[0][0][0])[i] = 0;
        (&h2_s[0][0][0])[i] = 0;
    }

    // ---- per-wave weight B-fragments (pre-scaled by -log2e; gate g: -2log2e) ----
    // layer-1 waves: Wf[0..1] = Whh1 K-halves.  layer-2: Wf[0..1]=Wih2, Wf[2..3]=Whh2.
    // (rh=0/1 wave pairs hold identical copies.)
    bf16x8 Wf[4][4];
    float wxc[4], bcs[4];
    #pragma unroll
    for (int g = 0; g < 4; ++g) {
        const float sc = (g == 2) ? (-2.0f * LOG2E) : (-LOG2E);
        const int col = g * 64 + ct * 16 + l15;
        if (!is2) {
            wxc[g] = Wih1[col] * sc;
            bcs[g] = (bih1[col] + bhh1[col]) * sc;
        } else {
            wxc[g] = 0.0f;
            bcs[g] = (bih2[col] + bhh2[col]) * sc;
        }
        #pragma unroll
        for (int kt = 0; kt < 2; ++kt) {
            const int koff = kt * 32 + quad * 8;
            union { short s[8]; bf16x8 v; } u0, u1;
            #pragma unroll
            for (int j = 0; j < 8; ++j) {
                if (!is2) {
                    u0.s[j] = f2bf(Whh1[col * HID + koff + j] * sc);
                    u1.s[j] = 0;
                } else {
                    u0.s[j] = f2bf(Wih2[col * HID + koff + j] * sc);
                    u1.s[j] = f2bf(Whh2[col * HID + koff + j] * sc);
                }
            }
            Wf[kt][g] = u0.v;
            Wf[2 + kt][g] = u1.v;
        }
    }

    const int hcol  = ct * 16 + l15;
    const int rbase = quad * 4 + rh * 2;   // first of this wave's two output rows
    float cst[2] = {0, 0};

#define L1_ROW(r, cr) { \
        float h1v = lstm_gate(z[0][r], z[1][r], z[2][r], z[3][r], cr); \
        h1_s[pr2][quad * 4 + (r)][hcol] = f2bf(h1v); }
#define L2_ROW(r, cr) { \
        float cc = cr; \
        float h2v = lstm_gate(z[0][r], z[1][r], z[2][r], z[3][r], cc) * m2; \
        cr = cc * m2; \
        h2_s[pr1][quad * 4 + (r)][hcol] = f2bf(h2v); }

    #pragma unroll 2
    for (int t = 0; t < SEQ; ++t) {
        const int pr1 = (t + 1) & 1;   // holds h1[t-1] / receives h2[t-1]
        const int pr2 = t & 1;         // holds h2[t-2] / receives h1[t]
        __syncthreads();
        if (!is2) {
            const bf16x8 A1a = *reinterpret_cast<const bf16x8*>(&h1_s[pr1][l15][quad * 8]);
            const bf16x8 A1b = *reinterpret_cast<const bf16x8*>(&h1_s[pr1][l15][32 + quad * 8]);
            floatx4 z[4];
            #pragma unroll
            for (int g = 0; g < 4; ++g)
                z[g] = floatx4{bcs[g], bcs[g], bcs[g], bcs[g]};
            // x contribution only for this wave's two rows (others are discarded)
            {
                const float xa = x_s[rbase][t];
                const float xb = x_s[rbase + 1][t];
                if (rh == 0) {
                    #pragma unroll
                    for (int g = 0; g < 4; ++g) {
                        z[g][0] += xa * wxc[g];
                        z[g][1] += xb * wxc[g];
                    }
                } else {
                    #pragma unroll
                    for (int g = 0; g < 4; ++g) {
                        z[g][2] += xa * wxc[g];
                        z[g][3] += xb * wxc[g];
                    }
                }
            }
            #pragma unroll
            for (int g = 0; g < 4; ++g) {
                z[g] = MFMA(A1a, Wf[0][g], z[g]);
                z[g] = MFMA(A1b, Wf[1][g], z[g]);
            }
            if (rh == 0) { L1_ROW(0, cst[0]); L1_ROW(1, cst[1]); }
            else         { L1_ROW(2, cst[0]); L1_ROW(3, cst[1]); }
        } else {
            const bf16x8 A1a = *reinterpret_cast<const bf16x8*>(&h1_s[pr1][l15][quad * 8]);
            const bf16x8 A1b = *reinterpret_cast<const bf16x8*>(&h1_s[pr1][l15][32 + quad * 8]);
            const bf16x8 A2a = *reinterpret_cast<const bf16x8*>(&h2_s[pr2][l15][quad * 8]);
            const bf16x8 A2b = *reinterpret_cast<const bf16x8*>(&h2_s[pr2][l15][32 + quad * 8]);
            floatx4 z[4];
            #pragma unroll
            for (int g = 0; g < 4; ++g)
                z[g] = floatx4{bcs[g], bcs[g], bcs[g], bcs[g]};
            #pragma unroll
            for (int g = 0; g < 4; ++g) {
                z[g] = MFMA(A1a, Wf[0][g], z[g]);   // Wih2 @ h1[t-1]
                z[g] = MFMA(A1b, Wf[1][g], z[g]);
                z[g] = MFMA(A2a, Wf[2][g], z[g]);   // Whh2 @ h2[t-2]
                z[g] = MFMA(A2b, Wf[3][g], z[g]);
            }
            const float m2 = (t == 0) ? 0.0f : 1.0f;  // discard bogus step at t=0
            if (rh == 0) { L2_ROW(0, cst[0]); L2_ROW(1, cst[1]); }
            else         { L2_ROW(2, cst[0]); L2_ROW(3, cst[1]); }
        }
    }

    // ---- drain: layer 2 for t = SEQ-1 (layer-2 waves only) ----
    __syncthreads();
    if (is2) {
        const bf16x8 A1a = *reinterpret_cast<const bf16x8*>(&h1_s[1][l15][quad * 8]);       // h1[511]
        const bf16x8 A1b = *reinterpret_cast<const bf16x8*>(&h1_s[1][l15][32 + quad * 8]);
        const bf16x8 A2a = *reinterpret_cast<const bf16x8*>(&h2_s[0][l15][quad * 8]);       // h2[510]
        const bf16x8 A2b = *reinterpret_cast<const bf16x8*>(&h2_s[0][l15][32 + quad * 8]);
        floatx4 z[4];
        #pragma unroll
        for (int g = 0; g < 4; ++g) {
            z[g] = floatx4{bcs[g], bcs[g], bcs[g], bcs[g]};
            z[g] = MFMA(A1a, Wf[0][g], z[g]);
            z[g] = MFMA(A1b, Wf[1][g], z[g]);
            z[g] = MFMA(A2a, Wf[2][g], z[g]);
            z[g] = MFMA(A2b, Wf[3][g], z[g]);
        }
        float* h2f = &x_s[0][0];                    // repurpose x stage as [16][64] f32
#define DR_ROW(r, cr) { \
            float cc = cr; \
            float h2v = lstm_gate(z[0][r], z[1][r], z[2][r], z[3][r], cc); \
            h2f[(quad * 4 + (r)) * HID + hcol] = h2v; }
        if (rh == 0) { DR_ROW(0, cst[0]); DR_ROW(1, cst[1]); }
        else         { DR_ROW(2, cst[0]); DR_ROW(3, cst[1]); }
    }
    __syncthreads();

    // ---- epilogue: relu(h2 @ Wd1^T + bd1) @ Wd2^T + bd2 ----
    const float* h2f = &x_s[0][0];
    for (int idx = tid; idx < 16 * 32; idx += 1024) {
        const int b = idx >> 5, o = idx & 31;
        float acc = bd1[o];
        #pragma unroll 8
        for (int k = 0; k < HID; ++k) acc += h2f[b * HID + k] * Wd1[o * HID + k];
        y1_s[b][o] = fmaxf(acc, 0.0f);
    }
    __syncthreads();
    for (int idx = tid; idx < 16 * 24; idx += 1024) {
        const int b = idx / 24, o = idx - b * 24;
        float acc = bd2[o];
        #pragma unroll 8
        for (int k = 0; k < 32; ++k) acc += y1_s[b][k] * Wd2[o * 32 + k];
        out[(size_t)(b0 + b) * 24 + o] = acc;
    }
}

extern "C" void kernel_launch(void* const* d_in, const int* in_sizes, int n_in,
                              void* d_out, int out_size, void* d_ws, size_t ws_size,
                              hipStream_t stream) {
    const float* x    = (const float*)d_in[0];
    const float* Wih1 = (const float*)d_in[1];
    const float* Whh1 = (const float*)d_in[2];
    const float* bih1 = (const float*)d_in[3];
    const float* bhh1 = (const float*)d_in[4];
    const float* Wih2 = (const float*)d_in[5];
    const float* Whh2 = (const float*)d_in[6];
    const float* bih2 = (const float*)d_in[7];
    const float* bhh2 = (const float*)d_in[8];
    const float* Wd1  = (const float*)d_in[9];
    const float* bd1  = (const float*)d_in[10];
    const float* Wd2  = (const float*)d_in[11];
    const float* bd2  = (const float*)d_in[12];
    float* out = (float*)d_out;

    lstm_fused<<<256, 1024, 0, stream>>>(x, Wih1, Whh1, bih1, bhh1,
                                         Wih2, Whh2, bih2, bhh2,
                                         Wd1, bd1, Wd2, bd2, out);
}

// Round 3
// 592.621 us; speedup vs baseline: 1.3785x; 1.3785x over previous
//
#include <hip/hip_runtime.h>

// Fused 2-layer LSTM (B=4096, S=512, H=64) + dense(64->32 relu)->dense(32->24).
// R6: R4 wave structure (1024 thr, 16 waves = 4/SIMD, grid=256) with the spill
// fixed BY CONSTRUCTION:
//  (a) LDS padded >80KB so only 1 WG/CU fits -> backend's occupancy analysis
//      (which drives the VGPR budget; attributes were ignored in R5) targets
//      4 waves/EU -> 128 VGPR budget instead of 64+spill. Also guarantees even
//      1-WG-per-CU dispatch (2-WG capacity + grid=256 risks stacking).
//  (b) t-loop split by layer (wave-uniform is2; barrier counts match 512+1 per
//      side): layer-1 waves hold only Wf[2][4] (32 VGPR), layer-2 Wf[4][4] (64);
//      peak pressure ~76/~110 < 128 -> no spill.
// R4/R5 post-mortem: VGPR clamped to 64, ~60B/thread scratch (WRITE_SIZE
// 0.38->15.8MB), per-step scratch reloads serialized the t-loop (3860 cy/step).
// Waves: (layer, col-tile, row-half). rh=0/1 pairs duplicate MFMAs (~20% pipe)
// but split gate math + h-write 2 rows each; 4 waves/SIMD hide each other's
// serial chain (barrier -> ds_read -> MFMA -> exp2 chain -> ds_write).
// Single barrier/step via parity double-buffered h1/h2 (layer-2 delayed 1 step:
// z2[t-1] = b2 + Wih2@h1[t-1] + Whh2@h2[t-2]).
// Gate math: 5 exp + 2 rcp per element (i/f/g denominators merged).

typedef __attribute__((ext_vector_type(8))) short bf16x8;
typedef __attribute__((ext_vector_type(4))) float floatx4;

#define SEQ 512
#define HID 64
#define LOG2E 1.4426950408889634f

__device__ inline floatx4 MFMA(bf16x8 a, bf16x8 b, floatx4 c) {
    return __builtin_amdgcn_mfma_f32_16x16x32_bf16(a, b, c, 0, 0, 0);
}
__device__ inline short f2bf(float f) {
    __bf16 b = (__bf16)f;
    return __builtin_bit_cast(short, b);
}
__device__ inline float exp2_fast(float x) {
#if __has_builtin(__builtin_amdgcn_exp2f)
    return __builtin_amdgcn_exp2f(x);
#else
    return __expf(x * 0.6931471805599453f);
#endif
}
__device__ inline float rcp_fast(float x) { return __builtin_amdgcn_rcpf(x); }

// z* pre-scaled: zi=-i*log2e, zf=-f*log2e, zg=-2g*log2e, zo=-o*log2e.
// c' = [c*(1+ei)(1+eg) + (1-eg)(1+ef)] / [(1+ef)(1+ei)(1+eg)]  (merged rcp)
// h  = sigm(o)*tanh(c') = (1-ec)/((1+eo)(1+ec)),  ec = e^{-2c'} (clamped)
__device__ inline float lstm_gate(float zi, float zf, float zg, float zo, float& c) {
    float ei = exp2_fast(zi);
    float ef = exp2_fast(zf);
    float eg = exp2_fast(zg);
    float eo = exp2_fast(zo);
    float P  = (1.0f + ei) * (1.0f + eg);
    float F  = 1.0f + ef;
    float num = c * P + (1.0f - eg) * F;
    c = num * rcp_fast(P * F);
    float ec = exp2_fast(fminf(c * (-2.0f * LOG2E), 40.0f));
    return (1.0f - ec) * rcp_fast((1.0f + eo) * (1.0f + ec));
}

__global__ __launch_bounds__(1024)
void lstm_fused(
    const float* __restrict__ x,
    const float* __restrict__ Wih1, const float* __restrict__ Whh1,
    const float* __restrict__ bih1, const float* __restrict__ bhh1,
    const float* __restrict__ Wih2, const float* __restrict__ Whh2,
    const float* __restrict__ bih2, const float* __restrict__ bhh2,
    const float* __restrict__ Wd1,  const float* __restrict__ bd1,
    const float* __restrict__ Wd2,  const float* __restrict__ bd2,
    float* __restrict__ out)
{
    const int tid  = threadIdx.x;
    const int wid  = tid >> 6;        // 0..15
    const int ct   = wid & 3;         // column-tile (h-cols [16ct,16ct+16))
    const int is2  = (wid >> 2) & 1;  // 0: layer-1 wave, 1: layer-2 wave
    const int rh   = wid >> 3;        // row-half: handles r in {2rh, 2rh+1}
    const int lane = tid & 63;
    const int l15  = lane & 15;
    const int quad = lane >> 4;
    const int b0   = blockIdx.x * 16;

    __shared__ __align__(16) float x_s[16][516];
    __shared__ __align__(16) short h1_s[2][16][72];
    __shared__ __align__(16) short h2_s[2][16][72];
    __shared__ float y1_s[16][32];
    // Occupancy clamp: push LDS past 80KB so only 1 WG/CU fits -> regalloc
    // budget becomes 128 VGPR (4 waves/EU) instead of 64 (8 waves/EU, spills).
    __shared__ float pad_s[10240];
    if (blockIdx.x == 0xFFFFFFFFu) ((volatile float*)pad_s)[tid] = 1.0f;  // never true; keeps pad_s allocated

    // ---- stage x tile (16 rows x 512 f32), 1024 threads ----
    {
        const int row = wid;               // 16 rows, one wave each
        const int c0  = lane * 8;          // 64 lanes x 8 floats = 512
        const float4* src = reinterpret_cast<const float4*>(x + (size_t)(b0 + row) * SEQ + c0);
        float4* dst = reinterpret_cast<float4*>(&x_s[row][c0]);
        dst[0] = src[0];
        dst[1] = src[1];
    }
    for (int i = tid; i < 2 * 16 * 72; i += 1024) {
        (&h1_s[0][0][0])[i] = 0;
        (&h2_s[0][0][0])[i] = 0;
    }

    const int hcol  = ct * 16 + l15;
    const int rbase = quad * 4 + rh * 2;   // first of this wave's two output rows

#define L1_ROW(r, cr) { \
        float h1v = lstm_gate(z[0][r], z[1][r], z[2][r], z[3][r], cr); \
        h1_s[pr2][quad * 4 + (r)][hcol] = f2bf(h1v); }
#define L2_ROW(r, cr) { \
        float cc = cr; \
        float h2v = lstm_gate(z[0][r], z[1][r], z[2][r], z[3][r], cc) * m2; \
        cr = cc * m2; \
        h2_s[pr1][quad * 4 + (r)][hcol] = f2bf(h2v); }

    if (!is2) {
        // ================= layer-1 waves =================
        bf16x8 Wf[2][4];                 // Whh1 K-halves, 32 VGPR
        float wxc[4], bcs[4];
        #pragma unroll
        for (int g = 0; g < 4; ++g) {
            const float sc = (g == 2) ? (-2.0f * LOG2E) : (-LOG2E);
            const int col = g * 64 + ct * 16 + l15;
            wxc[g] = Wih1[col] * sc;
            bcs[g] = (bih1[col] + bhh1[col]) * sc;
            #pragma unroll
            for (int kt = 0; kt < 2; ++kt) {
                const int koff = kt * 32 + quad * 8;
                union { short s[8]; bf16x8 v; } u;
                #pragma unroll
                for (int j = 0; j < 8; ++j)
                    u.s[j] = f2bf(Whh1[col * HID + koff + j] * sc);
                Wf[kt][g] = u.v;
            }
        }
        float cst[2] = {0, 0};
        #pragma unroll 2
        for (int t = 0; t < SEQ; ++t) {
            const int pr1 = (t + 1) & 1;   // holds h1[t-1]
            const int pr2 = t & 1;         // receives h1[t]
            __syncthreads();
            const bf16x8 A1a = *reinterpret_cast<const bf16x8*>(&h1_s[pr1][l15][quad * 8]);
            const bf16x8 A1b = *reinterpret_cast<const bf16x8*>(&h1_s[pr1][l15][32 + quad * 8]);
            const float xa = x_s[rbase][t];
            const float xb = x_s[rbase + 1][t];
            floatx4 z[4];
            #pragma unroll
            for (int g = 0; g < 4; ++g) {
                z[g] = floatx4{bcs[g], bcs[g], bcs[g], bcs[g]};
                if (rh == 0) { z[g][0] += xa * wxc[g]; z[g][1] += xb * wxc[g]; }
                else         { z[g][2] += xa * wxc[g]; z[g][3] += xb * wxc[g]; }
            }
            #pragma unroll
            for (int g = 0; g < 4; ++g) z[g] = MFMA(A1a, Wf[0][g], z[g]);
            #pragma unroll
            for (int g = 0; g < 4; ++g) z[g] = MFMA(A1b, Wf[1][g], z[g]);
            if (rh == 0) { L1_ROW(0, cst[0]); L1_ROW(1, cst[1]); }
            else         { L1_ROW(2, cst[0]); L1_ROW(3, cst[1]); }
        }
        __syncthreads();                  // drain-sync (matches layer-2 side)
    } else {
        // ================= layer-2 waves =================
        bf16x8 Wf[4][4];                 // Wih2 (0..1) + Whh2 (2..3), 64 VGPR
        float bcs[4];
        #pragma unroll
        for (int g = 0; g < 4; ++g) {
            const float sc = (g == 2) ? (-2.0f * LOG2E) : (-LOG2E);
            const int col = g * 64 + ct * 16 + l15;
            bcs[g] = (bih2[col] + bhh2[col]) * sc;
            #pragma unroll
            for (int kt = 0; kt < 2; ++kt) {
                const int koff = kt * 32 + quad * 8;
                union { short s[8]; bf16x8 v; } u0, u1;
                #pragma unroll
                for (int j = 0; j < 8; ++j) {
                    u0.s[j] = f2bf(Wih2[col * HID + koff + j] * sc);
                    u1.s[j] = f2bf(Whh2[col * HID + koff + j] * sc);
                }
                Wf[kt][g] = u0.v;
                Wf[2 + kt][g] = u1.v;
            }
        }
        float cst[2] = {0, 0};
        #pragma unroll 2
        for (int t = 0; t < SEQ; ++t) {
            const int pr1 = (t + 1) & 1;   // receives h2[t-1]
            const int pr2 = t & 1;         // holds h2[t-2]
            __syncthreads();
            floatx4 z[4];
            #pragma unroll
            for (int g = 0; g < 4; ++g)
                z[g] = floatx4{bcs[g], bcs[g], bcs[g], bcs[g]};
            {
                const bf16x8 A = *reinterpret_cast<const bf16x8*>(&h1_s[pr1][l15][quad * 8]);
                #pragma unroll
                for (int g = 0; g < 4; ++g) z[g] = MFMA(A, Wf[0][g], z[g]);   // Wih2 @ h1[t-1]
            }
            {
                const bf16x8 A = *reinterpret_cast<const bf16x8*>(&h1_s[pr1][l15][32 + quad * 8]);
                #pragma unroll
                for (int g = 0; g < 4; ++g) z[g] = MFMA(A, Wf[1][g], z[g]);
            }
            {
                const bf16x8 A = *reinterpret_cast<const bf16x8*>(&h2_s[pr2][l15][quad * 8]);
                #pragma unroll
                for (int g = 0; g < 4; ++g) z[g] = MFMA(A, Wf[2][g], z[g]);   // Whh2 @ h2[t-2]
            }
            {
                const bf16x8 A = *reinterpret_cast<const bf16x8*>(&h2_s[pr2][l15][32 + quad * 8]);
                #pragma unroll
                for (int g = 0; g < 4; ++g) z[g] = MFMA(A, Wf[3][g], z[g]);
            }
            const float m2 = (t == 0) ? 0.0f : 1.0f;  // discard bogus step at t=0
            if (rh == 0) { L2_ROW(0, cst[0]); L2_ROW(1, cst[1]); }
            else         { L2_ROW(2, cst[0]); L2_ROW(3, cst[1]); }
        }
        __syncthreads();                  // drain-sync: h1[511] now visible
        // ---- drain: layer 2 for t = SEQ-1 ----
        {
            const bf16x8 A1a = *reinterpret_cast<const bf16x8*>(&h1_s[1][l15][quad * 8]);       // h1[511]
            const bf16x8 A1b = *reinterpret_cast<const bf16x8*>(&h1_s[1][l15][32 + quad * 8]);
            const bf16x8 A2a = *reinterpret_cast<const bf16x8*>(&h2_s[0][l15][quad * 8]);       // h2[510]
            const bf16x8 A2b = *reinterpret_cast<const bf16x8*>(&h2_s[0][l15][32 + quad * 8]);
            floatx4 z[4];
            #pragma unroll
            for (int g = 0; g < 4; ++g) {
                z[g] = floatx4{bcs[g], bcs[g], bcs[g], bcs[g]};
                z[g] = MFMA(A1a, Wf[0][g], z[g]);
                z[g] = MFMA(A1b, Wf[1][g], z[g]);
                z[g] = MFMA(A2a, Wf[2][g], z[g]);
                z[g] = MFMA(A2b, Wf[3][g], z[g]);
            }
            float* h2f = &x_s[0][0];                    // repurpose x stage as [16][64] f32
#define DR_ROW(r, cr) { \
            float cc = cr; \
            float h2v = lstm_gate(z[0][r], z[1][r], z[2][r], z[3][r], cc); \
            h2f[(quad * 4 + (r)) * HID + hcol] = h2v; }
            if (rh == 0) { DR_ROW(0, cst[0]); DR_ROW(1, cst[1]); }
            else         { DR_ROW(2, cst[0]); DR_ROW(3, cst[1]); }
        }
    }
    __syncthreads();

    // ---- epilogue: relu(h2 @ Wd1^T + bd1) @ Wd2^T + bd2 ----
    const float* h2f = &x_s[0][0];
    for (int idx = tid; idx < 16 * 32; idx += 1024) {
        const int b = idx >> 5, o = idx & 31;
        float acc = bd1[o];
        #pragma unroll 8
        for (int k = 0; k < HID; ++k) acc += h2f[b * HID + k] * Wd1[o * HID + k];
        y1_s[b][o] = fmaxf(acc, 0.0f);
    }
    __syncthreads();
    for (int idx = tid; idx < 16 * 24; idx += 1024) {
        const int b = idx / 24, o = idx - b * 24;
        float acc = bd2[o];
        #pragma unroll 8
        for (int k = 0; k < 32; ++k) acc += y1_s[b][k] * Wd2[o * 32 + k];
        out[(size_t)(b0 + b) * 24 + o] = acc;
    }
}

extern "C" void kernel_launch(void* const* d_in, const int* in_sizes, int n_in,
                              void* d_out, int out_size, void* d_ws, size_t ws_size,
                              hipStream_t stream) {
    const float* x    = (const float*)d_in[0];
    const float* Wih1 = (const float*)d_in[1];
    const float* Whh1 = (const float*)d_in[2];
    const float* bih1 = (const float*)d_in[3];
    const float* bhh1 = (const float*)d_in[4];
    const float* Wih2 = (const float*)d_in[5];
    const float* Whh2 = (const float*)d_in[6];
    const float* bih2 = (const float*)d_in[7];
    const float* bhh2 = (const float*)d_in[8];
    const float* Wd1  = (const float*)d_in[9];
    const float* bd1  = (const float*)d_in[10];
    const float* Wd2  = (const float*)d_in[11];
    const float* bd2  = (const float*)d_in[12];
    float* out = (float*)d_out;

    lstm_fused<<<256, 1024, 0, stream>>>(x, Wih1, Whh1, bih1, bhh1,
                                         Wih2, Whh2, bih2, bhh2,
                                         Wd1, bd1, Wd2, bd2, out);
}